// Round 1
// baseline (1322.576 us; speedup 1.0000x reference)
//
#include <hip/hip_runtime.h>

// Problem constants (fixed by the reference)
constexpr int Mdim = 32;      // b*c
constexpr int Kdim = 16384;   // rows*cols
constexpr int Ndim = 16384;   // h*w

constexpr int TPB  = 256;     // build_xa / reduce block
constexpr int GTPB = 512;     // gemm block: 8 waves

// GEMM tiling: block = BN cols x KC k-rows, staged via LDS in 16-row slabs.
// BN=512 -> every global_load_lds request is 1 KB contiguous (2 KB per V row)
// => near-full DRAM page utilization (vs 128 B/row scattered before).
constexpr int BN     = 512;
constexpr int NB     = Ndim / BN;      // 32 n-blocks
constexpr int KT     = 16;             // split-K chunks
constexpr int KC     = Kdim / KT;      // 1024 k per block
constexpr int NSTAGE = KC / 16;        // 64 double-buffered stages

typedef short bf16x8 __attribute__((ext_vector_type(8)));   // 8 bf16 = 4 VGPR
typedef float f32x16 __attribute__((ext_vector_type(16)));  // 32x32 C/D frag

// fp32 -> bf16 RNE (proven: absmax 0.0039) — used for image (A side) only.
__device__ __forceinline__ short f32_to_bf16(float f) {
    union { float f; unsigned u; } c; c.f = f;
    unsigned u = c.u;
    u += 0x7fffu + ((u >> 16) & 1u);
    return (short)(u >> 16);
}

// ---------------------------------------------------------------------------
// Phase 0: A-fragments of x for 32x32x16 MFMA, bf16, scaled 1/128. Unchanged.
//   slab = k/16; lane holds A[m = lane&31][k = slab*16 + (lane>>5)*8 + j]
// ---------------------------------------------------------------------------
__global__ __launch_bounds__(TPB)
void build_xa(const float* __restrict__ image, short* __restrict__ xa) {
    const int g    = blockIdx.x * TPB + threadIdx.x;   // 0 .. 65535
    const int lane = g & 63;
    const int slab = g >> 6;                           // 0 .. 1023
    const int m    = lane & 31;
    const int k    = slab * 16 + (lane >> 5) * 8;
    const float* src = image + (size_t)m * Kdim + k;

    bf16x8 o;
    #pragma unroll
    for (int j = 0; j < 8; ++j)
        o[j] = f32_to_bf16(fmaxf(src[j], 0.0f) * (1.0f / 128.0f));
    reinterpret_cast<bf16x8*>(xa)[g] = o;
}

// ---------------------------------------------------------------------------
// global -> LDS direct DMA, 16 B per lane. LDS dest is wave-uniform base;
// HW adds lane*16 (linear). Global src is per-lane (contiguous 1 KB/instr).
// ---------------------------------------------------------------------------
__device__ __forceinline__ void glds16(const float* src, float* dst) {
    __builtin_amdgcn_global_load_lds(
        (const __attribute__((address_space(1))) void*)src,
        (__attribute__((address_space(3))) void*)dst,
        16, 0, 0);
}

// ---------------------------------------------------------------------------
// Phase 1: LDS-staged split-K GEMM.
//   Block: 8 waves, BN=512 cols, KC=1024 rows, 64 stages of 16 k-rows.
//   Stage: 32 KB fp32 slab, double-buffered (64 KB LDS, 2 blocks/CU).
//   Per wave/stage: 4x global_load_lds (1 KB each) + 1 A-frag load,
//   then counted s_waitcnt vmcnt(5) + raw s_barrier (prefetch never drained).
//   Fragment read: 16x ds_read_b32, 2-way bank alias (free). V is binary so
//   bf16 cast = exact hi-16 truncation (products bit-identical to prev ver).
// ---------------------------------------------------------------------------
__global__ __launch_bounds__(GTPB, 4)
void ht_gemm(const short* __restrict__ xa,    // A-fragments (bf16)
             const float* __restrict__ vote,  // (K, N) fp32
             float* __restrict__ parts)       // (KT, 32, N) fp32 partials
{
    __shared__ float vbuf[2][16 * BN];        // 2 x 32 KB

    const int tid  = threadIdx.x;
    const int lane = tid & 63;
    const int w    = tid >> 6;                // wave 0..7
    const int nb   = blockIdx.x & (NB - 1);
    const int kch  = blockIdx.x >> 5;         // NB == 32
    const int k0   = kch * KC;
    const int n0   = nb * BN;

    const int nlo  = lane & 31;
    const int krow = (lane >> 5) * 8;         // 0 or 8 within slab
    const int r0   = 2 * w;                   // this wave stages rows r0, r0+1

    const short* abase = xa + ((size_t)(k0 / 16) * 64 + lane) * 8;

    f32x16 acc0, acc1;
    #pragma unroll
    for (int i = 0; i < 16; ++i) { acc0[i] = 0.0f; acc1[i] = 0.0f; }

    auto stage = [&](int buf, int s) {
        const float* rp = vote + (size_t)(k0 + s * 16 + r0) * Ndim + n0;
        #pragma unroll
        for (int i = 0; i < 4; ++i) {         // rows r0,r0+1 x two 1 KB halves
            const float* src = rp + (size_t)(i >> 1) * Ndim + (i & 1) * 256 + lane * 4;
            glds16(src, &vbuf[buf][(r0 + (i >> 1)) * BN + (i & 1) * 256]);
        }
    };

    // Prologue: slab 0 in flight (4 DMA + 1 A-load = 5 vmem).
    stage(0, 0);
    bf16x8 aC = *reinterpret_cast<const bf16x8*>(abase);

    int cur = 0;
    for (int s = 0; s < NSTAGE; ++s) {
        bf16x8 aN = aC;
        if (s + 1 < NSTAGE) {
            stage(cur ^ 1, s + 1);            // 4 DMA into other buffer
            aN = *reinterpret_cast<const bf16x8*>(abase + (size_t)(s + 1) * 512);
            // Keep exactly this iteration's 5 vmem in flight; drain everything
            // older (= current buffer's DMAs). vmcnt drains oldest-first.
            asm volatile("s_waitcnt vmcnt(5)" ::: "memory");
        } else {
            asm volatile("s_waitcnt vmcnt(0)" ::: "memory");
        }
        __builtin_amdgcn_s_barrier();         // all waves drained their DMAs
        asm volatile("" ::: "memory");        // fence: no ds_read hoists above

        // B-fragments: lane holds V[k = krow+j][n], n = nlo (+32 for frag 1).
        // addr stride j*BN*4 = 2 KB -> imm offsets; lanes 0-31 consecutive,
        // lanes 32-63 at +16 KB -> same banks, 2 lanes/bank (free).
        const float* vb = &vbuf[cur][krow * BN + w * 64 + nlo];
        bf16x8 b0, b1;
        #pragma unroll
        for (int j = 0; j < 8; ++j) {
            union { float f; unsigned u; } c0, c1;
            c0.f = vb[j * BN];
            c1.f = vb[j * BN + 32];
            b0[j] = (short)(c0.u >> 16);      // exact for V in {0,1}
            b1[j] = (short)(c1.u >> 16);
        }
        acc0 = __builtin_amdgcn_mfma_f32_32x32x16_bf16(aC, b0, acc0, 0, 0, 0);
        acc1 = __builtin_amdgcn_mfma_f32_32x32x16_bf16(aC, b1, acc1, 0, 0, 0);

        __builtin_amdgcn_s_barrier();         // all waves done reading buf[cur]
        asm volatile("" ::: "memory");
        aC = aN; cur ^= 1;
    }

    // Epilogue: C/D col = lane&31, row = (reg&3) + 8*(reg>>2) + 4*(lane>>5)
    // [m74/m101-verified]. 128 B contiguous segments per store.
    float* pb = parts + (size_t)kch * ((size_t)Mdim * Ndim);
    const int c0    = n0 + w * 64 + nlo;
    const int rbase = 4 * (lane >> 5);
    #pragma unroll
    for (int r = 0; r < 16; ++r) {
        const int row = (r & 3) + 8 * (r >> 2) + rbase;
        pb[(size_t)row * Ndim + c0]      = acc0[r];
        pb[(size_t)row * Ndim + c0 + 32] = acc1[r];
    }
}

// ---------------------------------------------------------------------------
// Phase 2: out[i] = sum_c parts[c][i]
// ---------------------------------------------------------------------------
__global__ __launch_bounds__(TPB)
void ht_reduce(const float* __restrict__ parts, float* __restrict__ out, int nchunks) {
    const size_t i4 = (size_t)blockIdx.x * TPB + threadIdx.x;
    const float4* p = reinterpret_cast<const float4*>(parts) + i4;
    float4 s = make_float4(0.f, 0.f, 0.f, 0.f);
    constexpr size_t stride4 = (size_t)Mdim * Ndim / 4;
    for (int c = 0; c < nchunks; ++c) {
        const float4 v = p[(size_t)c * stride4];
        s.x += v.x; s.y += v.y; s.z += v.z; s.w += v.w;
    }
    reinterpret_cast<float4*>(out)[i4] = s;
}

// ---------------------------------------------------------------------------
// Fallback (tiny ws): fp32 atomic version — correct, slower.
// ---------------------------------------------------------------------------
__global__ __launch_bounds__(TPB)
void ht_gemm_atomic(const float* __restrict__ image, const float* __restrict__ vote,
                    float* __restrict__ out) {
    __shared__ float xsh[256 * Mdim];
    const int tid = threadIdx.x;
    const int ntile = blockIdx.x % 16;
    const int k0 = (blockIdx.x / 16) * 256;
    const int nn0 = ntile * 1024 + tid * 4;
    for (int idx = tid; idx < 256 * Mdim; idx += TPB) {
        const int kk = idx >> 5, m = idx & 31;
        xsh[idx] = fmaxf(image[(size_t)m * Kdim + (k0 + kk)], 0.0f) * (1.0f / 128.0f);
    }
    __syncthreads();
    float4 acc[Mdim];
    #pragma unroll
    for (int m = 0; m < Mdim; ++m) acc[m] = make_float4(0.f, 0.f, 0.f, 0.f);
    const float* vptr = vote + (size_t)k0 * Ndim + nn0;
    for (int kk = 0; kk < 256; ++kk) {
        const float4 v = *reinterpret_cast<const float4*>(vptr);
        vptr += Ndim;
        #pragma unroll
        for (int m = 0; m < Mdim; ++m) {
            const float s = xsh[kk * Mdim + m];
            acc[m].x = fmaf(s, v.x, acc[m].x); acc[m].y = fmaf(s, v.y, acc[m].y);
            acc[m].z = fmaf(s, v.z, acc[m].z); acc[m].w = fmaf(s, v.w, acc[m].w);
        }
    }
    #pragma unroll
    for (int m = 0; m < Mdim; ++m) {
        float* o = out + (size_t)m * Ndim + nn0;
        unsafeAtomicAdd(o + 0, acc[m].x); unsafeAtomicAdd(o + 1, acc[m].y);
        unsafeAtomicAdd(o + 2, acc[m].z); unsafeAtomicAdd(o + 3, acc[m].w);
    }
}

extern "C" void kernel_launch(void* const* d_in, const int* in_sizes, int n_in,
                              void* d_out, int out_size, void* d_ws, size_t ws_size,
                              hipStream_t stream) {
    const float* image = (const float*)d_in[0];   // (32, 16384)
    const float* vote  = (const float*)d_in[1];   // (16384, 16384)
    float* out = (float*)d_out;                   // (32, 16384)

    const size_t xa_bytes    = (size_t)(Kdim / 16) * 64 * 8 * sizeof(short);   // 1 MB
    const size_t chunk_bytes = (size_t)Mdim * Ndim * sizeof(float);            // 2 MB

    if (xa_bytes + (size_t)KT * chunk_bytes > ws_size) {
        (void)hipMemsetAsync(out, 0, (size_t)out_size * sizeof(float), stream);
        ht_gemm_atomic<<<dim3(16 * 64), TPB, 0, stream>>>(image, vote, out);
        return;
    }

    short* xa    = (short*)d_ws;
    float* parts = (float*)((char*)d_ws + xa_bytes);

    build_xa<<<dim3((Kdim / 16) * 64 / TPB), TPB, 0, stream>>>(image, xa);
    ht_gemm<<<dim3(NB * KT), GTPB, 0, stream>>>(xa, vote, parts);
    ht_reduce<<<dim3((Mdim * Ndim) / (4 * TPB)), TPB, 0, stream>>>(parts, out, KT);
}

// Round 3
// 1309.893 us; speedup vs baseline: 1.0097x; 1.0097x over previous
//
#include <hip/hip_runtime.h>

// Problem constants (fixed by the reference)
constexpr int Mdim = 32;      // b*c
constexpr int Kdim = 16384;   // rows*cols
constexpr int Ndim = 16384;   // h*w

constexpr int TPB  = 256;     // build_xa / reduce block
constexpr int GTPB = 512;     // gemm block: 8 waves

// GEMM tiling: block = BN cols x KC k-rows, 16-row slabs through a 4-buffer
// LDS ring, lead-2 DMA prefetch. Discipline (race-proof, same as proven R1):
//   per phase: issue(s+2) -> WAITV(6) drains OWN stage-s trio -> s_barrier
//   (now ALL waves' stage-s DMAs are in LDS) -> compute(s).
// Ring safety needs NBUF >= lead+2 = 4: buffer (s+2)%4 overwritten at phase s
// was last read at phase s-2, a full barrier earlier.
constexpr int BN     = 256;
constexpr int NB     = Ndim / BN;      // 64 n-blocks
constexpr int KT     = 8;              // split-K chunks
constexpr int KC     = Kdim / KT;      // 2048 k per block
constexpr int NSTAGE = KC / 16;        // 128 stages (divisible by 4)
// LDS: 4 x 16KB = 64 KB -> 2 blocks/CU, grid 512 = exactly co-resident.

typedef short bf16x8 __attribute__((ext_vector_type(8)));   // 8 bf16 = 4 VGPR
typedef float f32x16 __attribute__((ext_vector_type(16)));  // 32x32 C/D frag

// fp32 -> bf16 RNE (proven: absmax 0.0039) — used for image (A side) only.
__device__ __forceinline__ short f32_to_bf16(float f) {
    union { float f; unsigned u; } c; c.f = f;
    unsigned u = c.u;
    u += 0x7fffu + ((u >> 16) & 1u);
    return (short)(u >> 16);
}

// ---------------------------------------------------------------------------
// Phase 0: A-fragments of x for 32x32x16 MFMA, bf16, scaled 1/128. Unchanged.
//   slab = k/16; lane holds A[m = lane&31][k = slab*16 + (lane>>5)*8 + j]
// ---------------------------------------------------------------------------
__global__ __launch_bounds__(TPB)
void build_xa(const float* __restrict__ image, short* __restrict__ xa) {
    const int g    = blockIdx.x * TPB + threadIdx.x;   // 0 .. 65535
    const int lane = g & 63;
    const int slab = g >> 6;                           // 0 .. 1023
    const int m    = lane & 31;
    const int k    = slab * 16 + (lane >> 5) * 8;
    const float* src = image + (size_t)m * Kdim + k;

    bf16x8 o;
    #pragma unroll
    for (int j = 0; j < 8; ++j)
        o[j] = f32_to_bf16(fmaxf(src[j], 0.0f) * (1.0f / 128.0f));
    reinterpret_cast<bf16x8*>(xa)[g] = o;
}

// global -> LDS direct DMA, 16 B per lane. LDS dest wave-uniform (+lane*16 HW);
// global src per-lane (contiguous 1 KB per instruction = one full BN row).
__device__ __forceinline__ void glds16(const float* src, float* dst) {
    __builtin_amdgcn_global_load_lds(
        (const __attribute__((address_space(1))) void*)src,
        (__attribute__((address_space(3))) void*)dst,
        16, 0, 0);
}

#define BARRIER() do { asm volatile("" ::: "memory"); \
                       __builtin_amdgcn_s_barrier();  \
                       asm volatile("" ::: "memory"); } while (0)
#define WAITV(n) asm volatile("s_waitcnt vmcnt(" #n ")" ::: "memory")

// ---------------------------------------------------------------------------
// Phase 1: LDS-staged split-K GEMM, lead-2 / 4-buffer ring.
//   Block: 8 waves, BN=256 cols, KC=2048 rows, 128 stages of 16 k-rows.
//   Per wave per phase: one trio = {2x global_load_lds (rows r0,r0+1) +
//   1 A-frag global load} -> 3 vmem. Steady state keeps 2 lead trios (6 vmem)
//   in flight across the barrier; WAITV(6) drains exactly the current
//   stage's trio BEFORE s_barrier, so post-barrier the slab is complete
//   from every wave. Phase gap to drain ~= 2 full phases >> HBM latency.
// ---------------------------------------------------------------------------
__global__ __launch_bounds__(GTPB, 4)
void ht_gemm(const short* __restrict__ xa,    // A-fragments (bf16)
             const float* __restrict__ vote,  // (K, N) fp32
             float* __restrict__ parts)       // (KT, 32, N) fp32 partials
{
    __shared__ float vbuf[4][16 * BN];        // 4 x 16 KB ring

    const int tid  = threadIdx.x;
    const int lane = tid & 63;
    const int w    = tid >> 6;                // wave 0..7
    const int nb   = blockIdx.x & (NB - 1);
    const int kch  = blockIdx.x >> 6;         // NB == 64
    const int k0   = kch * KC;
    const int n0   = nb * BN;

    const int nlo  = lane & 31;
    const int krow = (lane >> 5) * 8;         // 0 or 8 within slab
    const int r0   = 2 * w;                   // this wave stages rows r0, r0+1

    const short* abase = xa + ((size_t)(k0 / 16) * 64 + lane) * 8;

    f32x16 acc;
    #pragma unroll
    for (int i = 0; i < 16; ++i) acc[i] = 0.0f;

    bf16x8 ar0, ar1, ar2, ar3;                // A-ring: ar[i] holds stage s, s&3==i

    // Issue stage s's trio into ring buffer b (b == s&3): 2 DMA rows + A-frag.
    auto issue = [&](int b, int s, bf16x8& ar) {
        const float* rp = vote + (size_t)(k0 + s * 16 + r0) * Ndim + n0 + lane * 4;
        glds16(rp,        &vbuf[b][(r0)     * BN]);
        glds16(rp + Ndim, &vbuf[b][(r0 + 1) * BN]);
        ar = *reinterpret_cast<const bf16x8*>(abase + (size_t)s * 512);
    };
    // Consume ring buffer b: 8 ds_read_b32 (2 lanes/bank, free) + exact hi-16
    // truncation (V is binary {0,1}) + one 32x32x16 MFMA.
    auto compute = [&](int b, bf16x8 ar) {
        const float* vb = &vbuf[b][krow * BN + w * 32 + nlo];
        bf16x8 bf;
        #pragma unroll
        for (int j = 0; j < 8; ++j) {
            union { float f; unsigned u; } c; c.f = vb[j * BN];
            bf[j] = (short)(c.u >> 16);       // exact for V in {0,1}
        }
        acc = __builtin_amdgcn_mfma_f32_32x32x16_bf16(ar, bf, acc, 0, 0, 0);
    };

    // Prologue: 2 trios in flight (6 vmem).
    issue(0, 0, ar0);
    issue(1, 1, ar1);

    // Main loop: phases 0 .. NSTAGE-5, issuing stages 2 .. NSTAGE-1.
    for (int s0 = 0; s0 < NSTAGE - 4; s0 += 4) {
        issue(2, s0 + 2, ar2); WAITV(6); BARRIER(); compute(0, ar0);
        issue(3, s0 + 3, ar3); WAITV(6); BARRIER(); compute(1, ar1);
        issue(0, s0 + 4, ar0); WAITV(6); BARRIER(); compute(2, ar2);
        issue(1, s0 + 5, ar1); WAITV(6); BARRIER(); compute(3, ar3);
    }
    // Tail: phases NSTAGE-4 .. NSTAGE-1 (last issues: stages NSTAGE-2, NSTAGE-1).
    issue(2, NSTAGE - 2, ar2); WAITV(6); BARRIER(); compute(0, ar0);
    issue(3, NSTAGE - 1, ar3); WAITV(6); BARRIER(); compute(1, ar1);
    /* no issue */             WAITV(3); BARRIER(); compute(2, ar2);
    /* no issue */             WAITV(0); BARRIER(); compute(3, ar3);

    // Epilogue: C/D col = lane&31, row = (reg&3) + 8*(reg>>2) + 4*(lane>>5)
    // [m74/m101-verified]. 128 B contiguous segments per store.
    float* pb = parts + (size_t)kch * ((size_t)Mdim * Ndim);
    const int c0    = n0 + w * 32 + nlo;
    const int rbase = 4 * (lane >> 5);
    #pragma unroll
    for (int r = 0; r < 16; ++r) {
        const int row = (r & 3) + 8 * (r >> 2) + rbase;
        pb[(size_t)row * Ndim + c0] = acc[r];
    }
}

// ---------------------------------------------------------------------------
// Phase 2: out[i] = sum_c parts[c][i]
// ---------------------------------------------------------------------------
__global__ __launch_bounds__(TPB)
void ht_reduce(const float* __restrict__ parts, float* __restrict__ out, int nchunks) {
    const size_t i4 = (size_t)blockIdx.x * TPB + threadIdx.x;
    const float4* p = reinterpret_cast<const float4*>(parts) + i4;
    float4 s = make_float4(0.f, 0.f, 0.f, 0.f);
    constexpr size_t stride4 = (size_t)Mdim * Ndim / 4;
    for (int c = 0; c < nchunks; ++c) {
        const float4 v = p[(size_t)c * stride4];
        s.x += v.x; s.y += v.y; s.z += v.z; s.w += v.w;
    }
    reinterpret_cast<float4*>(out)[i4] = s;
}

// ---------------------------------------------------------------------------
// Fallback (tiny ws): fp32 atomic version — correct, slower.
// ---------------------------------------------------------------------------
__global__ __launch_bounds__(TPB)
void ht_gemm_atomic(const float* __restrict__ image, const float* __restrict__ vote,
                    float* __restrict__ out) {
    __shared__ float xsh[256 * Mdim];
    const int tid = threadIdx.x;
    const int ntile = blockIdx.x % 16;
    const int k0 = (blockIdx.x / 16) * 256;
    const int nn0 = ntile * 1024 + tid * 4;
    for (int idx = tid; idx < 256 * Mdim; idx += TPB) {
        const int kk = idx >> 5, m = idx & 31;
        xsh[idx] = fmaxf(image[(size_t)m * Kdim + (k0 + kk)], 0.0f) * (1.0f / 128.0f);
    }
    __syncthreads();
    float4 acc[Mdim];
    #pragma unroll
    for (int m = 0; m < Mdim; ++m) acc[m] = make_float4(0.f, 0.f, 0.f, 0.f);
    const float* vptr = vote + (size_t)k0 * Ndim + nn0;
    for (int kk = 0; kk < 256; ++kk) {
        const float4 v = *reinterpret_cast<const float4*>(vptr);
        vptr += Ndim;
        #pragma unroll
        for (int m = 0; m < Mdim; ++m) {
            const float s = xsh[kk * Mdim + m];
            acc[m].x = fmaf(s, v.x, acc[m].x); acc[m].y = fmaf(s, v.y, acc[m].y);
            acc[m].z = fmaf(s, v.z, acc[m].z); acc[m].w = fmaf(s, v.w, acc[m].w);
        }
    }
    #pragma unroll
    for (int m = 0; m < Mdim; ++m) {
        float* o = out + (size_t)m * Ndim + nn0;
        unsafeAtomicAdd(o + 0, acc[m].x); unsafeAtomicAdd(o + 1, acc[m].y);
        unsafeAtomicAdd(o + 2, acc[m].z); unsafeAtomicAdd(o + 3, acc[m].w);
    }
}

extern "C" void kernel_launch(void* const* d_in, const int* in_sizes, int n_in,
                              void* d_out, int out_size, void* d_ws, size_t ws_size,
                              hipStream_t stream) {
    const float* image = (const float*)d_in[0];   // (32, 16384)
    const float* vote  = (const float*)d_in[1];   // (16384, 16384)
    float* out = (float*)d_out;                   // (32, 16384)

    const size_t xa_bytes    = (size_t)(Kdim / 16) * 64 * 8 * sizeof(short);   // 1 MB
    const size_t chunk_bytes = (size_t)Mdim * Ndim * sizeof(float);            // 2 MB

    if (xa_bytes + (size_t)KT * chunk_bytes > ws_size) {
        (void)hipMemsetAsync(out, 0, (size_t)out_size * sizeof(float), stream);
        ht_gemm_atomic<<<dim3(16 * 64), TPB, 0, stream>>>(image, vote, out);
        return;
    }

    short* xa    = (short*)d_ws;
    float* parts = (float*)((char*)d_ws + xa_bytes);

    build_xa<<<dim3((Kdim / 16) * 64 / TPB), TPB, 0, stream>>>(image, xa);
    ht_gemm<<<dim3(NB * KT), GTPB, 0, stream>>>(xa, vote, parts);
    ht_reduce<<<dim3((Mdim * Ndim) / (4 * TPB)), TPB, 0, stream>>>(parts, out, KT);
}